// Round 12
// baseline (1946.625 us; speedup 1.0000x reference)
//
#include <hip/hip_runtime.h>
#include <stdint.h>

#define KVOL 27
#define CIN  32
#define COUT 64
#define RB   64          // output rows per bin-block (6-bit rowlocal)
#define SCAN_CHUNK 4096
#define NSEG  10
#define SEGBLK 313       // out64-blocks per segment (last = 308)
#define SEGCAP 288000    // contrib rows per segment (mean 270432, +35 sigma)

typedef __attribute__((ext_vector_type(8))) short bf16x8;
typedef __attribute__((ext_vector_type(4))) float f32x4;

__device__ __forceinline__ ushort f2bf(float f) {
  uint32_t u = __float_as_uint(f);
  u += 0x7FFFu + ((u >> 16) & 1u);   // RNE
  return (ushort)(u >> 16);
}

__device__ __forceinline__ uint32_t cvtpk(float lo, float hi) {
  uint32_t r;
  asm("v_cvt_pk_bf16_f32 %0, %1, %2" : "=v"(r) : "v"(lo), "v"(hi));
  return r;
}

// ---------------------------------------------------------------------------
// feat fp32 -> bf16 rows (64B/row)  [verified r3/r9]
// ---------------------------------------------------------------------------
__global__ __launch_bounds__(256) void feat_cvt_kernel(const float* __restrict__ feat,
                                                       ushort* __restrict__ feat16,
                                                       int total4) {
  int i = blockIdx.x * 256 + threadIdx.x;
  if (i < total4) {
    float4 v = ((const float4*)feat)[i];
    ushort4 o;
    o.x = f2bf(v.x); o.y = f2bf(v.y); o.z = f2bf(v.z); o.w = f2bf(v.w);
    ((ushort4*)feat16)[i] = o;
  }
}

// ---------------------------------------------------------------------------
// weights fp32 -> bf16 B-frag layout kernT[ko][ct][col16][k32]  [verified r3-9]
// ---------------------------------------------------------------------------
__global__ __launch_bounds__(256) void kern_cvt_kernel(const float* __restrict__ kern,
                                                       ushort* __restrict__ kernT) {
  int tid = blockIdx.x * 256 + threadIdx.x;
  int kc   = tid & 3;
  int colq = (tid >> 2) & 15;
  int ct   = (tid >> 6) & 3;
  int ko   = tid >> 8;
  if (ko >= KVOL) return;
  const float* src = kern + (size_t)ko * CIN * COUT + ct * 16 + colq;
  ushort tmp[8];
#pragma unroll
  for (int j = 0; j < 8; ++j) tmp[j] = f2bf(src[(size_t)(kc * 8 + j) * COUT]);
  ushort* dst = kernT + (((size_t)(ko * 4 + ct) * 16 + colq) * 32 + kc * 8);
#pragma unroll
  for (int j = 0; j < 8; ++j) dst[j] = tmp[j];
}

// ---------------------------------------------------------------------------
// prep: out64-major bins (verified r10): bin = (out>>6)*27 + k
// ---------------------------------------------------------------------------
__global__ __launch_bounds__(256) void hist_kernel(const int4* __restrict__ kmap2,
                                                   int* __restrict__ count, int M2) {
  int t = blockIdx.x * 256 + threadIdx.x;
  int k = blockIdx.y;
  if (t < M2) {
    int4 v = kmap2[(size_t)k * M2 + t];
    atomicAdd(&count[(v.y >> 6) * KVOL + k], 1);
    atomicAdd(&count[(v.w >> 6) * KVOL + k], 1);
  }
}

__global__ __launch_bounds__(256) void scan_reduce(const int* __restrict__ count,
                                                   int* __restrict__ partial, int nb) {
  __shared__ int ws[4];
  int t = threadIdx.x;
  int base = blockIdx.x * SCAN_CHUNK + t * 16;
  int s = 0;
#pragma unroll
  for (int i = 0; i < 16; ++i) { int idx = base + i; if (idx < nb) s += count[idx]; }
  for (int d = 32; d; d >>= 1) s += __shfl_down(s, d);
  if ((t & 63) == 0) ws[t >> 6] = s;
  __syncthreads();
  if (t == 0) partial[blockIdx.x] = ws[0] + ws[1] + ws[2] + ws[3];
}

__global__ __launch_bounds__(64) void scan_partials(int* __restrict__ partial,
                                                    int nchunks, int* __restrict__ total_out) {
  int lane = threadIdx.x;
  int run = 0;
  for (int base = 0; base < nchunks; base += 64) {
    int i = base + lane;
    int orig = (i < nchunks) ? partial[i] : 0;
    int v = orig;
    for (int d = 1; d < 64; d <<= 1) { int u = __shfl_up(v, d); if (lane >= d) v += u; }
    if (i < nchunks) partial[i] = run + v - orig;
    run += __shfl(v, 63);
  }
  if (lane == 0) *total_out = run;
}

__global__ __launch_bounds__(256) void scan_down(const int* __restrict__ count,
                                                 const int* __restrict__ partial,
                                                 int* __restrict__ start,
                                                 int* __restrict__ cursor, int nb) {
  __shared__ int wsum[4];
  int t = threadIdx.x, blk = blockIdx.x;
  int base = blk * SCAN_CHUNK + t * 16;
  int v[16]; int s = 0;
#pragma unroll
  for (int i = 0; i < 16; ++i) { int idx = base + i; v[i] = (idx < nb) ? count[idx] : 0; s += v[i]; }
  int lane = t & 63, wv = t >> 6;
  int sv = s;
  for (int d = 1; d < 64; d <<= 1) { int u = __shfl_up(sv, d); if (lane >= d) sv += u; }
  if (lane == 63) wsum[wv] = sv;
  __syncthreads();
  int wbase = 0;
  for (int i = 0; i < wv; ++i) wbase += wsum[i];
  int prefix = partial[blk] + wbase + (sv - s);
#pragma unroll
  for (int i = 0; i < 16; ++i) {
    int idx = base + i;
    if (idx < nb) { start[idx] = prefix; cursor[idx] = prefix; }
    prefix += v[i];
  }
}

__global__ __launch_bounds__(256) void scatter_kernel(const int4* __restrict__ kmap2,
                                                      int* __restrict__ cursor,
                                                      uint32_t* __restrict__ binned, int M2) {
  int t = blockIdx.x * 256 + threadIdx.x;
  int k = blockIdx.y;
  if (t < M2) {
    int4 v = kmap2[(size_t)k * M2 + t];
    int p1 = atomicAdd(&cursor[(v.y >> 6) * KVOL + k], 1);
    binned[p1] = (uint32_t)v.x | ((uint32_t)(v.y & 63) << 18);
    int p2 = atomicAdd(&cursor[(v.w >> 6) * KVOL + k], 1);
    binned[p2] = (uint32_t)v.z | ((uint32_t)(v.w & 63) << 18);
  }
}

// ---------------------------------------------------------------------------
// PHASE 1 (streaming GEMM): one wave per bin. Per 16-entry batch: CSR entry
// load -> own-chunk feat16 gather (lane (q,g), r3-verified A-frag) -> 4 MFMA
// from zero -> pack D to bf16 (cvt_pk pairs) -> ONE dwordx2 store per reg at
// contrib16[pos][q*4+ct] (col-permuted row, 128B fully coalesced). No LDS, no
// atomics, no inter-batch deps. 8.4K independent waves per launch.
// ---------------------------------------------------------------------------
__global__ __launch_bounds__(256) void phase1_gemm(
    const ushort* __restrict__ feat16,    // [N][CIN] bf16
    const uint32_t* __restrict__ binned,  // [E] CSR by bin
    const int* __restrict__ start,        // [NBIN+1]
    const ushort* __restrict__ kernT,     // [KVOL][4][16][32] bf16
    ushort* __restrict__ contrib16,       // [SEGCAP][64] bf16, col-permuted
    int firstBin, int nbins) {
  const int wv = threadIdx.x >> 6;
  const int l  = threadIdx.x & 63;
  const int q  = l & 15;          // entry slot / col-within-tile
  const int g  = l >> 4;          // feat chunk / D row group
  int wid = blockIdx.x * 4 + wv;
  if (wid >= nbins) return;
  const int bin = firstBin + wid;
  const int segBase = start[firstBin];
  const int s0 = start[bin];
  const int cnt = start[bin + 1] - s0;
  if (cnt <= 0) return;
  const int k = bin % KVOL;

  const ushort* kb = kernT + ((size_t)k * 64 + q) * 32 + g * 8;
  const bf16x8 b0 = *(const bf16x8*)(kb);
  const bf16x8 b1 = *(const bf16x8*)(kb + 512);
  const bf16x8 b2 = *(const bf16x8*)(kb + 1024);
  const bf16x8 b3 = *(const bf16x8*)(kb + 1536);

  for (int base = 0; base < cnt; base += 16) {
    int cb = cnt - base; if (cb > 16) cb = 16;
    uint32_t e = binned[s0 + base + (q < cb ? q : cb - 1)];
    bf16x8 a = {0, 0, 0, 0, 0, 0, 0, 0};
    if (q < cb)
      a = *(const bf16x8*)(feat16 + (size_t)(e & 0x3FFFFu) * CIN + g * 8);
    f32x4 z = {0.f, 0.f, 0.f, 0.f};
    f32x4 c0 = __builtin_amdgcn_mfma_f32_16x16x32_bf16(a, b0, z, 0, 0, 0);
    f32x4 c1 = __builtin_amdgcn_mfma_f32_16x16x32_bf16(a, b1, z, 0, 0, 0);
    f32x4 c2 = __builtin_amdgcn_mfma_f32_16x16x32_bf16(a, b2, z, 0, 0, 0);
    f32x4 c3 = __builtin_amdgcn_mfma_f32_16x16x32_bf16(a, b3, z, 0, 0, 0);
    const int pbase = s0 - segBase + base;
#pragma unroll
    for (int reg = 0; reg < 4; ++reg) {
      int s = 4 * g + reg;                // D row = entry slot (r3-verified)
      int pl = pbase + s;
      if (s < cb && pl < SEGCAP) {
        uint2 pk;
        pk.x = cvtpk(c0[reg], c1[reg]);   // ushorts q*4+0 (ct0), q*4+1 (ct1)
        pk.y = cvtpk(c2[reg], c3[reg]);   // ushorts q*4+2 (ct2), q*4+3 (ct3)
        ((uint2*)(contrib16 + (size_t)pl * 64))[q] = pk;
      }
    }
  }
}

// ---------------------------------------------------------------------------
// PHASE 2 (streaming reduce): one block per out64-block. Contiguous contrib
// range split across 4 waves; per row: rl tag from binned, 2B/lane permuted
// row read (one 128B line), fire-and-forget ds_add into tile[rl][lane].
// Writeout + bias once. Pure streaming: sequential lines, unroll 4.
// ---------------------------------------------------------------------------
__global__ __launch_bounds__(256) void phase2_reduce(
    const ushort* __restrict__ contrib16,
    const uint32_t* __restrict__ binned,
    const int* __restrict__ start,
    const float* __restrict__ bias,
    float* __restrict__ out,
    int firstBlk) {
  __shared__ float tile[RB][COUT + 1];
  const int wv = threadIdx.x >> 6;
  const int l  = threadIdx.x & 63;
  const int ob = firstBlk + blockIdx.x;
  const int segBase = start[firstBlk * KVOL];
  const int lo = start[ob * KVOL];
  int hi = start[ob * KVOL + KVOL];
  if (hi - segBase > SEGCAP) hi = segBase + SEGCAP;  // mirror phase1 guard

  for (int i = threadIdx.x; i < RB * (COUT + 1); i += 256)
    ((float*)tile)[i] = 0.f;
  __syncthreads();

  const int perm = (l & 15) * 4 + (l >> 4);   // col l lives at q*4+ct
  const int m = hi - lo;
  const int per = (m + 3) >> 2;
  int myLo = lo + wv * per;
  int myHi = myLo + per; if (myHi > hi) myHi = hi;

  int i = myLo;
  for (; i + 4 <= myHi; i += 4) {
    uint32_t e0 = binned[i], e1 = binned[i + 1], e2 = binned[i + 2], e3 = binned[i + 3];
    const size_t p = (size_t)(i - segBase) * 64 + perm;
    float v0 = __uint_as_float((uint32_t)contrib16[p]       << 16);
    float v1 = __uint_as_float((uint32_t)contrib16[p + 64]  << 16);
    float v2 = __uint_as_float((uint32_t)contrib16[p + 128] << 16);
    float v3 = __uint_as_float((uint32_t)contrib16[p + 192] << 16);
    atomicAdd(&tile[(e0 >> 18) & 63][l], v0);
    atomicAdd(&tile[(e1 >> 18) & 63][l], v1);
    atomicAdd(&tile[(e2 >> 18) & 63][l], v2);
    atomicAdd(&tile[(e3 >> 18) & 63][l], v3);
  }
  for (; i < myHi; ++i) {
    uint32_t e = binned[i];
    float v = __uint_as_float(
        (uint32_t)contrib16[(size_t)(i - segBase) * 64 + perm] << 16);
    atomicAdd(&tile[(e >> 18) & 63][l], v);
  }
  __syncthreads();

  const float bv = bias[l];
  const int R0 = ob * RB;
  for (int r = wv; r < RB; r += 4)
    out[(size_t)(R0 + r) * COUT + l] = tile[r][l] + bv;
}

// ---------------------------------------------------------------------------
extern "C" void kernel_launch(void* const* d_in, const int* in_sizes, int n_in,
                              void* d_out, int out_size, void* d_ws, size_t ws_size,
                              hipStream_t stream) {
  const float* feat  = (const float*)d_in[0];
  const int4*  kmap2 = (const int4*)d_in[3];   // 2 pairs per int4
  const float* kern  = (const float*)d_in[4];
  const float* bias  = (const float*)d_in[5];
  float* out = (float*)d_out;

  const int N = in_sizes[0] / CIN;            // 200000
  const int M = in_sizes[3] / (2 * KVOL);     // 100000
  const int M2 = M / 2;                       // 50000
  const int NBLK = N / RB;                    // 3125
  const int NBIN = NBLK * KVOL;               // 84375

  // workspace (~62 MB total)
  ushort* feat16 = (ushort*)d_ws;                       // 12.8 MB
  ushort* kernT  = feat16 + (size_t)N * CIN;            // 110 KB
  int* count   = (int*)(kernT + (size_t)KVOL * CIN * COUT);
  int* startA  = count + NBIN;                          // NBIN+1
  int* cursor  = startA + NBIN + 1;
  int* partial = cursor + NBIN;                         // 64
  uint32_t* binned = (uint32_t*)(partial + 64);         // 10.8 MB
  ushort* contrib16 = (ushort*)(binned + (size_t)KVOL * M);  // 36.9 MB

  const int nchunks = (NBIN + SCAN_CHUNK - 1) / SCAN_CHUNK;   // 21

  hipMemsetAsync(count, 0, (size_t)NBIN * sizeof(int), stream);
  hipLaunchKernelGGL(feat_cvt_kernel, dim3((N * CIN / 4 + 255) / 256), dim3(256), 0, stream,
                     feat, feat16, N * CIN / 4);
  hipLaunchKernelGGL(kern_cvt_kernel, dim3(KVOL), dim3(256), 0, stream, kern, kernT);

  dim3 pgrid((M2 + 255) / 256, KVOL);
  hipLaunchKernelGGL(hist_kernel, pgrid, dim3(256), 0, stream, kmap2, count, M2);
  hipLaunchKernelGGL(scan_reduce, dim3(nchunks), dim3(256), 0, stream, count, partial, NBIN);
  hipLaunchKernelGGL(scan_partials, dim3(1), dim3(64), 0, stream, partial, nchunks, startA + NBIN);
  hipLaunchKernelGGL(scan_down, dim3(nchunks), dim3(256), 0, stream,
                     count, partial, startA, cursor, NBIN);
  hipLaunchKernelGGL(scatter_kernel, pgrid, dim3(256), 0, stream, kmap2, cursor, binned, M2);

  for (int s = 0; s < NSEG; ++s) {
    int first = s * SEGBLK;
    if (first >= NBLK) break;
    int nb = NBLK - first; if (nb > SEGBLK) nb = SEGBLK;
    int nbins = nb * KVOL;
    hipLaunchKernelGGL(phase1_gemm, dim3((nbins + 3) / 4), dim3(256), 0, stream,
                       feat16, binned, startA, kernT, contrib16, first * KVOL, nbins);
    hipLaunchKernelGGL(phase2_reduce, dim3(nb), dim3(256), 0, stream,
                       contrib16, binned, startA, bias, out, first);
  }
}